// Round 1
// baseline (100.677 us; speedup 1.0000x reference)
//
#include <hip/hip_runtime.h>

// Problem constants (from reference setup_inputs)
constexpr int Bx = 8;
constexpr int Nn = 16384;   // power of two -> shift/mask index math
constexpr int Vv = 12;
constexpr long long TOT = (long long)Bx * Nn * Vv;   // 1,572,864 output elems

__device__ __forceinline__ float lk(float x) { return fmaxf(x, 0.2f * x); }

// Kernel 1: one thread per (b,n). Computes pre-BN y[b,v,n] into `y`
// (layout [B,V,N] == final output layout) and accumulates sum / sumsq.
__global__ __launch_bounds__(256) void nlmp_compute(
    const float* __restrict__ F,
    const float* __restrict__ W1, const float* __restrict__ b1,
    const float* __restrict__ W2, const float* __restrict__ b2,
    const float* __restrict__ W3, const float* __restrict__ b3,
    const float* __restrict__ cw, const float* __restrict__ cb,
    float* __restrict__ y, double* __restrict__ acc)
{
    const int t = blockIdx.x * blockDim.x + threadIdx.x;  // in [0, B*N)

    // tiny weight set: broadcast loads, L2/L1 cached
    const float w100 = W1[0], w101 = W1[1], w110 = W1[2], w111 = W1[3];
    const float bb10 = b1[0], bb11 = b1[1];
    const float w200 = W2[0], w201 = W2[1], w210 = W2[2], w211 = W2[3];
    const float bb20 = b2[0], bb21 = b2[1];
    const float w30 = W3[0], w31 = W3[1], bb3 = b3[0];
    const float c0 = cw[0], c1 = cw[1], cbv = cb[0];

    // F[b,n,0..11]: contiguous 48 B -> three float4 loads
    float f[Vv];
    const float4* fp = reinterpret_cast<const float4*>(F + (long long)t * Vv);
    float4 q0 = fp[0], q1 = fp[1], q2 = fp[2];
    f[0] = q0.x; f[1] = q0.y; f[2]  = q0.z; f[3]  = q0.w;
    f[4] = q1.x; f[5] = q1.y; f[6]  = q1.z; f[7]  = q1.w;
    f[8] = q2.x; f[9] = q2.y; f[10] = q2.z; f[11] = q2.w;

    // Layer-1 factored: h[c](i,j) = lk( W1[c,0]*F[j] + (W1[c,1]*F[i] + b1[c]) )
    float a0[Vv], a1[Vv], p0[Vv], p1[Vv];
#pragma unroll
    for (int v = 0; v < Vv; ++v) {
        a0[v] = w100 * f[v];
        a1[v] = w110 * f[v];
        p0[v] = fmaf(w101, f[v], bb10);
        p1[v] = fmaf(w111, f[v], bb11);
    }

    const int b = t >> 14;        // / 16384
    const int n = t & (Nn - 1);

    float s = 0.f, ss = 0.f;
#pragma unroll
    for (int i = 0; i < Vv; ++i) {
        float ms = 0.f;
#pragma unroll
        for (int j = 0; j < Vv; ++j) {
            float h0 = lk(a0[j] + p0[i]);
            float h1 = lk(a1[j] + p1[i]);
            float g0 = lk(fmaf(w200, h0, fmaf(w201, h1, bb20)));
            float g1 = lk(fmaf(w210, h0, fmaf(w211, h1, bb21)));
            ms += lk(fmaf(w30, g0, fmaf(w31, g1, bb3)));
        }
        float yv = fmaf(c0, f[i], fmaf(c1, ms, cbv));
        y[((long long)b * Vv + i) * Nn + n] = yv;   // coalesced per i across n
        s += yv;
        ss = fmaf(yv, yv, ss);
    }

    // wave(64) shuffle reduction, then block reduction, one atomic pair/block
#pragma unroll
    for (int off = 32; off > 0; off >>= 1) {
        s  += __shfl_down(s,  off, 64);
        ss += __shfl_down(ss, off, 64);
    }
    __shared__ float ls[4], lss[4];
    const int lane = threadIdx.x & 63;
    const int wave = threadIdx.x >> 6;
    if (lane == 0) { ls[wave] = s; lss[wave] = ss; }
    __syncthreads();
    if (threadIdx.x == 0) {
        float bs  = ls[0]  + ls[1]  + ls[2]  + ls[3];
        float bss = lss[0] + lss[1] + lss[2] + lss[3];
        atomicAdd(&acc[0], (double)bs);
        atomicAdd(&acc[1], (double)bss);
    }
}

// Kernel 2: in-place BN (training-mode batch stats) + leaky, float4-vectorized.
__global__ __launch_bounds__(256) void nlmp_finalize(
    float* __restrict__ y, const double* __restrict__ acc,
    const float* __restrict__ gamma, const float* __restrict__ beta)
{
    const long long idx4 = (long long)blockIdx.x * blockDim.x + threadIdx.x;
    const double mean = acc[0] / (double)TOT;
    const double var  = acc[1] / (double)TOT - mean * mean;
    const float scale = (float)(1.0 / sqrt(var + 1e-5)) * gamma[0];
    const float mb = (float)mean;
    const float bt = beta[0];

    float4 v = reinterpret_cast<float4*>(y)[idx4];
    float4 o;
    o.x = lk(fmaf(v.x - mb, scale, bt));
    o.y = lk(fmaf(v.y - mb, scale, bt));
    o.z = lk(fmaf(v.z - mb, scale, bt));
    o.w = lk(fmaf(v.w - mb, scale, bt));
    reinterpret_cast<float4*>(y)[idx4] = o;
}

extern "C" void kernel_launch(void* const* d_in, const int* in_sizes, int n_in,
                              void* d_out, int out_size, void* d_ws, size_t ws_size,
                              hipStream_t stream) {
    const float* F  = (const float*)d_in[0];
    const float* W1 = (const float*)d_in[1];
    const float* b1 = (const float*)d_in[2];
    const float* W2 = (const float*)d_in[3];
    const float* b2 = (const float*)d_in[4];
    const float* W3 = (const float*)d_in[5];
    const float* b3 = (const float*)d_in[6];
    const float* cw = (const float*)d_in[7];
    const float* cb = (const float*)d_in[8];
    const float* gamma = (const float*)d_in[9];
    const float* beta  = (const float*)d_in[10];

    float*  out = (float*)d_out;       // used as pre-BN scratch, then finalized in place
    double* acc = (double*)d_ws;       // 2 doubles: sum, sumsq

    hipMemsetAsync(d_ws, 0, 2 * sizeof(double), stream);

    nlmp_compute<<<(Bx * Nn) / 256, 256, 0, stream>>>(
        F, W1, b1, W2, b2, W3, b3, cw, cb, out, acc);

    nlmp_finalize<<<(int)(TOT / 4 / 256), 256, 0, stream>>>(out, acc, gamma, beta);
}

// Round 2
// 89.883 us; speedup vs baseline: 1.1201x; 1.1201x over previous
//
#include <hip/hip_runtime.h>

// Problem constants (from reference setup_inputs)
constexpr int Bx = 8;
constexpr int Nn = 16384;   // power of two -> shift/mask index math
constexpr int Vv = 12;
constexpr long long TOT = (long long)Bx * Nn * Vv;   // 1,572,864 output elems
constexpr int NB1 = (Bx * Nn) / 256;                 // 512 compute blocks

__device__ __forceinline__ float lk(float x) { return fmaxf(x, 0.2f * x); }

// Kernel 1: one thread per (b,n). Computes pre-BN y[b,v,n] into `y`
// (layout [B,V,N] == final output layout) and writes one float2 partial
// (sum, sumsq) per block into ws — plain store, no atomics, no init needed.
__global__ __launch_bounds__(256) void nlmp_compute(
    const float* __restrict__ F,
    const float* __restrict__ W1, const float* __restrict__ b1,
    const float* __restrict__ W2, const float* __restrict__ b2,
    const float* __restrict__ W3, const float* __restrict__ b3,
    const float* __restrict__ cw, const float* __restrict__ cb,
    float* __restrict__ y, float2* __restrict__ part)
{
    const int t = blockIdx.x * blockDim.x + threadIdx.x;  // in [0, B*N)

    // tiny weight set: broadcast loads, L2/L1 cached
    const float w100 = W1[0], w101 = W1[1], w110 = W1[2], w111 = W1[3];
    const float bb10 = b1[0], bb11 = b1[1];
    const float w200 = W2[0], w201 = W2[1], w210 = W2[2], w211 = W2[3];
    const float bb20 = b2[0], bb21 = b2[1];
    const float w30 = W3[0], w31 = W3[1], bb3 = b3[0];
    const float c0 = cw[0], c1 = cw[1], cbv = cb[0];

    // F[b,n,0..11]: contiguous 48 B -> three float4 loads
    float f[Vv];
    const float4* fp = reinterpret_cast<const float4*>(F + (long long)t * Vv);
    float4 q0 = fp[0], q1 = fp[1], q2 = fp[2];
    f[0] = q0.x; f[1] = q0.y; f[2]  = q0.z; f[3]  = q0.w;
    f[4] = q1.x; f[5] = q1.y; f[6]  = q1.z; f[7]  = q1.w;
    f[8] = q2.x; f[9] = q2.y; f[10] = q2.z; f[11] = q2.w;

    // Layer-1 factored: h[c](i,j) = lk( W1[c,0]*F[j] + (W1[c,1]*F[i] + b1[c]) )
    float a0[Vv], a1[Vv], p0[Vv], p1[Vv];
#pragma unroll
    for (int v = 0; v < Vv; ++v) {
        a0[v] = w100 * f[v];
        a1[v] = w110 * f[v];
        p0[v] = fmaf(w101, f[v], bb10);
        p1[v] = fmaf(w111, f[v], bb11);
    }

    const int b = t >> 14;        // / 16384
    const int n = t & (Nn - 1);

    float s = 0.f, ss = 0.f;
#pragma unroll
    for (int i = 0; i < Vv; ++i) {
        float ms = 0.f;
#pragma unroll
        for (int j = 0; j < Vv; ++j) {
            float h0 = lk(a0[j] + p0[i]);
            float h1 = lk(a1[j] + p1[i]);
            float g0 = lk(fmaf(w200, h0, fmaf(w201, h1, bb20)));
            float g1 = lk(fmaf(w210, h0, fmaf(w211, h1, bb21)));
            ms += lk(fmaf(w30, g0, fmaf(w31, g1, bb3)));
        }
        float yv = fmaf(c0, f[i], fmaf(c1, ms, cbv));
        y[((long long)b * Vv + i) * Nn + n] = yv;   // coalesced per i across n
        s += yv;
        ss = fmaf(yv, yv, ss);
    }

    // wave(64) shuffle reduction, then block reduction, one plain store/block
#pragma unroll
    for (int off = 32; off > 0; off >>= 1) {
        s  += __shfl_down(s,  off, 64);
        ss += __shfl_down(ss, off, 64);
    }
    __shared__ float ls[4], lss[4];
    const int lane = threadIdx.x & 63;
    const int wave = threadIdx.x >> 6;
    if (lane == 0) { ls[wave] = s; lss[wave] = ss; }
    __syncthreads();
    if (threadIdx.x == 0) {
        float2 p;
        p.x = ls[0]  + ls[1]  + ls[2]  + ls[3];
        p.y = lss[0] + lss[1] + lss[2] + lss[3];
        part[blockIdx.x] = p;
    }
}

// Kernel 2: every block redundantly reduces the 512 block-partials (4 KB,
// L2-resident), then applies BN (training-mode batch stats) + leaky in place.
__global__ __launch_bounds__(256) void nlmp_finalize(
    float* __restrict__ y, const float2* __restrict__ part,
    const float* __restrict__ gamma, const float* __restrict__ beta)
{
    const int t = threadIdx.x;

    // reduce 512 partials: thread t handles part[t] and part[t+256]
    float2 pa = part[t], pb = part[t + 256];
    float s  = pa.x + pb.x;
    float ss = pa.y + pb.y;
#pragma unroll
    for (int off = 32; off > 0; off >>= 1) {
        s  += __shfl_down(s,  off, 64);
        ss += __shfl_down(ss, off, 64);
    }
    __shared__ float ls[4], lss[4];
    __shared__ float coef[3];   // scale, mean, shift
    const int lane = t & 63;
    const int wave = t >> 6;
    if (lane == 0) { ls[wave] = s; lss[wave] = ss; }
    __syncthreads();
    if (t == 0) {
        double S  = (double)ls[0]  + ls[1]  + ls[2]  + ls[3];
        double SS = (double)lss[0] + lss[1] + lss[2] + lss[3];
        double mean = S / (double)TOT;
        double var  = SS / (double)TOT - mean * mean;
        coef[0] = (float)(1.0 / sqrt(var + 1e-5)) * gamma[0];
        coef[1] = (float)mean;
        coef[2] = beta[0];
    }
    __syncthreads();
    const float scale = coef[0], mb = coef[1], bt = coef[2];

    const long long idx4 = (long long)blockIdx.x * blockDim.x + t;
    float4 v = reinterpret_cast<float4*>(y)[idx4];
    float4 o;
    o.x = lk(fmaf(v.x - mb, scale, bt));
    o.y = lk(fmaf(v.y - mb, scale, bt));
    o.z = lk(fmaf(v.z - mb, scale, bt));
    o.w = lk(fmaf(v.w - mb, scale, bt));
    reinterpret_cast<float4*>(y)[idx4] = o;
}

extern "C" void kernel_launch(void* const* d_in, const int* in_sizes, int n_in,
                              void* d_out, int out_size, void* d_ws, size_t ws_size,
                              hipStream_t stream) {
    const float* F  = (const float*)d_in[0];
    const float* W1 = (const float*)d_in[1];
    const float* b1 = (const float*)d_in[2];
    const float* W2 = (const float*)d_in[3];
    const float* b2 = (const float*)d_in[4];
    const float* W3 = (const float*)d_in[5];
    const float* b3 = (const float*)d_in[6];
    const float* cw = (const float*)d_in[7];
    const float* cb = (const float*)d_in[8];
    const float* gamma = (const float*)d_in[9];
    const float* beta  = (const float*)d_in[10];

    float*  out  = (float*)d_out;      // pre-BN scratch, finalized in place
    float2* part = (float2*)d_ws;      // 512 block partials (sum, sumsq)

    nlmp_compute<<<NB1, 256, 0, stream>>>(
        F, W1, b1, W2, b2, W3, b3, cw, cb, out, part);

    nlmp_finalize<<<(int)(TOT / 4 / 256), 256, 0, stream>>>(out, part, gamma, beta);
}